// Round 1
// baseline (1568.948 us; speedup 1.0000x reference)
//
#include <hip/hip_runtime.h>

// Depthwise 7x7 cross-correlation, same padding.
// x:    [8, 256, 64, 64]   fp32
// tmpl: [8, 8, 256, 7, 7]  fp32  (nt, bs, nc, ht, wt)
// out:  [8, 8, 256, 64, 64] fp32
//
// One block per (b,c) plane; x staged into LDS once, reused by all 8 templates.
// v2: per-thread tile widened 4x4 -> 8x4 (1.43x fewer LDS row reads per output),
// and 2 templates processed concurrently (half-block each, wave-uniform) so the
// template loop has 4 rounds instead of 8 (half the tap-load stall points).
// __launch_bounds__(256,4) caps VGPR at 128 -> 4 waves/SIMD occupancy.
// LDS plane zero-padded: rows 0..69 (y = row-3), cols 0..71 (x = col-4; left
// pad 4 keeps ds_read_b128 16B-aligned). LSTR=72 gives an even 8-touch/bank
// distribution for the strided wave read (no conflict hotspot).

#define NT 8
#define BS 8
#define NC 256
#define HW 64
#define PLANE (HW * HW)          // 4096
#define LROWS 70
#define LSTR  72                 // row stride in floats; 288 B (16B mult)
#define TPL_STR 52               // padded template stride (4-aligned for float4)

__global__ __launch_bounds__(256, 4) void dwxcorr_kernel(
    const float* __restrict__ x,
    const float* __restrict__ tm,
    float* __restrict__ out)
{
    __shared__ __align__(16) float xpl[LROWS * LSTR];     // 20160 B
    __shared__ __align__(16) float tpl[NT * TPL_STR];     // 1664 B

    const int bc  = blockIdx.x;          // b*256 + c, 0..2047
    const int tid = threadIdx.x;

    // ---- zero the whole padded plane (pads must be 0) ----
    for (int i = tid; i < LROWS * LSTR; i += 256) xpl[i] = 0.0f;
    __syncthreads();

    // ---- stage x interior: 1024 float4 loads, coalesced ----
    const float* xp = x + bc * PLANE;
    for (int i = tid; i < PLANE / 4; i += 256) {
        float4 v = ((const float4*)xp)[i];
        int row = i >> 4;              // 16 float4 per 64-wide row
        int c4  = (i & 15) << 2;
        *(float4*)&xpl[(row + 3) * LSTR + 4 + c4] = v;
    }

    // ---- stage all 8 templates for this (b,c) ----
    const float* tb = tm + bc * 49;
    for (int i = tid; i < NT * 49; i += 256) {
        int t = i / 49;
        int k = i - t * 49;
        tpl[t * TPL_STR + k] = tb[t * (NT * NC * 49) + k];
    }
    __syncthreads();

    // ---- compute geometry: 128 threads cover the plane per template ----
    // half 0 (tid 0..127, waves 0-1) does template 2*rnd+0,
    // half 1 (tid 128..255, waves 2-3) does template 2*rnd+1 (wave-uniform t).
    const int half = tid >> 7;
    const int lid  = tid & 127;
    const int tx   = lid & 15;           // col group: cols 4*tx..4*tx+3
    const int ty   = lid >> 4;           // row group: rows 8*ty..8*ty+7
    const int col0 = tx << 2;
    const int row0 = ty << 3;

    for (int rnd = 0; rnd < 4; ++rnd) {
        const int t = (rnd << 1) + half;

        // broadcast template taps into registers (13 x ds_read_b128, same addr
        // across the wave -> LDS broadcast)
        float w[TPL_STR];
        const float4* wp = (const float4*)&tpl[t * TPL_STR];
        #pragma unroll
        for (int q = 0; q < TPL_STR / 4; ++q) {
            float4 v = wp[q];
            w[4 * q + 0] = v.x; w[4 * q + 1] = v.y;
            w[4 * q + 2] = v.z; w[4 * q + 3] = v.w;
        }

        float acc[8][4];
        #pragma unroll
        for (int r = 0; r < 8; ++r)
            #pragma unroll
            for (int j = 0; j < 4; ++j) acc[r][j] = 0.0f;

        // input rows for output rows row0..row0+7: LDS rows row0..row0+13
        #pragma unroll
        for (int ir = 0; ir < 14; ++ir) {
            const float* rowp = &xpl[(row0 + ir) * LSTR + col0];
            float xw[12];
            float4 a = *(const float4*)(rowp);
            float4 b = *(const float4*)(rowp + 4);
            float4 c = *(const float4*)(rowp + 8);
            xw[0] = a.x; xw[1]  = a.y; xw[2]  = a.z; xw[3]  = a.w;
            xw[4] = b.x; xw[5]  = b.y; xw[6]  = b.z; xw[7]  = b.w;
            xw[8] = c.x; xw[9]  = c.y; xw[10] = c.z; xw[11] = c.w;

            #pragma unroll
            for (int r = 0; r < 8; ++r) {
                const int ky = ir - r;            // compile-time after unroll
                if (ky >= 0 && ky < 7) {
                    #pragma unroll
                    for (int kx = 0; kx < 7; ++kx) {
                        const float tv = w[ky * 7 + kx];
                        #pragma unroll
                        for (int j = 0; j < 4; ++j)
                            acc[r][j] = fmaf(xw[j + kx + 1], tv, acc[r][j]);
                    }
                }
            }
        }

        // ---- store 8 rows x float4, coalesced across tx (256B runs) ----
        float* op = out + (size_t)(t * (BS * NC) + bc) * PLANE + row0 * HW + col0;
        #pragma unroll
        for (int r = 0; r < 8; ++r) {
            float4 v = make_float4(acc[r][0], acc[r][1], acc[r][2], acc[r][3]);
            *(float4*)(op + r * HW) = v;
        }
    }
}

extern "C" void kernel_launch(void* const* d_in, const int* in_sizes, int n_in,
                              void* d_out, int out_size, void* d_ws, size_t ws_size,
                              hipStream_t stream) {
    const float* x  = (const float*)d_in[0];
    const float* tm = (const float*)d_in[1];
    float* out = (float*)d_out;
    dwxcorr_kernel<<<BS * NC, 256, 0, stream>>>(x, tm, out);
}

// Round 2
// 789.402 us; speedup vs baseline: 1.9875x; 1.9875x over previous
//
#include <hip/hip_runtime.h>

// Depthwise 7x7 cross-correlation, same padding.
// x:    [8, 256, 64, 64]   fp32
// tmpl: [8, 8, 256, 7, 7]  fp32  (nt, bs, nc, ht, wt)
// out:  [8, 8, 256, 64, 64] fp32
//
// One block per (b,c) plane; x staged into LDS once, reused by all 8 templates.
// v3 = v2 structure (8x4 per-thread tile, 2 templates concurrently in half-
// blocks, 4 rounds) with the register budget fixed:
//   __launch_bounds__(256, 2)  -- NOT (256,4): empirically (256,4) capped the
//   allocator at 64 VGPRs (old 256-regs/wave model) and spilled ~50 regs ->
//   3 GB of scratch FETCH traffic, 1365 us. Demand here is ~115 VGPRs; the
//   (256,2) cap of 128 fits with margin and keeps 4 waves/SIMD.
// Bank conflicts measured negligible (8M cycles chip-wide ~= 1%): LSTR=72
// gives the even 8-lanes-per-16B-slot distribution, which is the b128 minimum.

#define NT 8
#define BS 8
#define NC 256
#define HW 64
#define PLANE (HW * HW)          // 4096
#define LROWS 70
#define LSTR  72                 // row stride in floats; 288 B (16B mult)
#define TPL_STR 52               // padded template stride (4-aligned for float4)

__global__ __launch_bounds__(256, 2) void dwxcorr_kernel(
    const float* __restrict__ x,
    const float* __restrict__ tm,
    float* __restrict__ out)
{
    __shared__ __align__(16) float xpl[LROWS * LSTR];     // 20160 B
    __shared__ __align__(16) float tpl[NT * TPL_STR];     // 1664 B

    const int bc  = blockIdx.x;          // b*256 + c, 0..2047
    const int tid = threadIdx.x;

    // ---- zero the whole padded plane (pads must be 0) ----
    for (int i = tid; i < LROWS * LSTR; i += 256) xpl[i] = 0.0f;
    __syncthreads();

    // ---- stage x interior: 1024 float4 loads, coalesced ----
    const float* xp = x + bc * PLANE;
    for (int i = tid; i < PLANE / 4; i += 256) {
        float4 v = ((const float4*)xp)[i];
        int row = i >> 4;              // 16 float4 per 64-wide row
        int c4  = (i & 15) << 2;
        *(float4*)&xpl[(row + 3) * LSTR + 4 + c4] = v;
    }

    // ---- stage all 8 templates for this (b,c) ----
    const float* tb = tm + bc * 49;
    for (int i = tid; i < NT * 49; i += 256) {
        int t = i / 49;
        int k = i - t * 49;
        tpl[t * TPL_STR + k] = tb[t * (NT * NC * 49) + k];
    }
    __syncthreads();

    // ---- compute geometry: 128 threads cover the plane per template ----
    // half 0 (tid 0..127, waves 0-1) does template 2*rnd+0,
    // half 1 (tid 128..255, waves 2-3) does template 2*rnd+1 (wave-uniform t).
    const int half = tid >> 7;
    const int lid  = tid & 127;
    const int tx   = lid & 15;           // col group: cols 4*tx..4*tx+3
    const int ty   = lid >> 4;           // row group: rows 8*ty..8*ty+7
    const int col0 = tx << 2;
    const int row0 = ty << 3;

    for (int rnd = 0; rnd < 4; ++rnd) {
        const int t = (rnd << 1) + half;

        // broadcast template taps into registers (13 x ds_read_b128, same addr
        // across the wave -> LDS broadcast)
        float w[TPL_STR];
        const float4* wp = (const float4*)&tpl[t * TPL_STR];
        #pragma unroll
        for (int q = 0; q < TPL_STR / 4; ++q) {
            float4 v = wp[q];
            w[4 * q + 0] = v.x; w[4 * q + 1] = v.y;
            w[4 * q + 2] = v.z; w[4 * q + 3] = v.w;
        }

        float acc[8][4];
        #pragma unroll
        for (int r = 0; r < 8; ++r)
            #pragma unroll
            for (int j = 0; j < 4; ++j) acc[r][j] = 0.0f;

        // input rows for output rows row0..row0+7: LDS rows row0..row0+13
        #pragma unroll
        for (int ir = 0; ir < 14; ++ir) {
            const float* rowp = &xpl[(row0 + ir) * LSTR + col0];
            float xw[12];
            float4 a = *(const float4*)(rowp);
            float4 b = *(const float4*)(rowp + 4);
            float4 c = *(const float4*)(rowp + 8);
            xw[0] = a.x; xw[1]  = a.y; xw[2]  = a.z; xw[3]  = a.w;
            xw[4] = b.x; xw[5]  = b.y; xw[6]  = b.z; xw[7]  = b.w;
            xw[8] = c.x; xw[9]  = c.y; xw[10] = c.z; xw[11] = c.w;

            #pragma unroll
            for (int r = 0; r < 8; ++r) {
                const int ky = ir - r;            // compile-time after unroll
                if (ky >= 0 && ky < 7) {
                    #pragma unroll
                    for (int kx = 0; kx < 7; ++kx) {
                        const float tv = w[ky * 7 + kx];
                        #pragma unroll
                        for (int j = 0; j < 4; ++j)
                            acc[r][j] = fmaf(xw[j + kx + 1], tv, acc[r][j]);
                    }
                }
            }
        }

        // ---- store 8 rows x float4, coalesced across tx (256B runs) ----
        float* op = out + (size_t)(t * (BS * NC) + bc) * PLANE + row0 * HW + col0;
        #pragma unroll
        for (int r = 0; r < 8; ++r) {
            float4 v = make_float4(acc[r][0], acc[r][1], acc[r][2], acc[r][3]);
            *(float4*)(op + r * HW) = v;
        }
    }
}

extern "C" void kernel_launch(void* const* d_in, const int* in_sizes, int n_in,
                              void* d_out, int out_size, void* d_ws, size_t ws_size,
                              hipStream_t stream) {
    const float* x  = (const float*)d_in[0];
    const float* tm = (const float*)d_in[1];
    float* out = (float*)d_out;
    dwxcorr_kernel<<<BS * NC, 256, 0, stream>>>(x, tm, out);
}

// Round 3
// 365.857 us; speedup vs baseline: 4.2884x; 2.1577x over previous
//
#include <hip/hip_runtime.h>

// Depthwise 7x7 cross-correlation, same padding.
// x:    [8, 256, 64, 64]   fp32
// tmpl: [8, 8, 256, 7, 7]  fp32  (nt, bs, nc, ht, wt)
// out:  [8, 8, 256, 64, 64] fp32
//
// One block per (b,c) plane; x staged into LDS once, reused by all 8 templates.
// Structure: 8x4 per-thread output tile, 2 templates processed concurrently
// (half-block each, wave-uniform t), 4 rounds.
//
// v4: __launch_bounds__(256) with NO min-wave arg. Empirically on this
// toolchain the 2nd arg sets VGPR cap = 256/arg: (256,4)->64 cap (huge spill,
// 3 GB scratch, 1365us), (256,2)->128 cap (partial spill, 0.9 GB scratch,
// 441us). True demand with the unrolled 14-row loop is ~150-190 (acc 32 +
// taps 49 + 2-3 pipelined 12-float windows + addressing), so the cap must go.
// 3 waves/SIMD at <=170 VGPR is fine: 32 independent FMA chains give deep ILP.
// Bank conflicts measured negligible (~1% of cycles): LSTR=72 yields the even
// 8-lanes-per-16B-slot distribution, the b128 minimum.

#define NT 8
#define BS 8
#define NC 256
#define HW 64
#define PLANE (HW * HW)          // 4096
#define LROWS 70
#define LSTR  72                 // row stride in floats; 288 B (16B mult)
#define TPL_STR 52               // padded template stride (4-aligned for float4)

__global__ __launch_bounds__(256) void dwxcorr_kernel(
    const float* __restrict__ x,
    const float* __restrict__ tm,
    float* __restrict__ out)
{
    __shared__ __align__(16) float xpl[LROWS * LSTR];     // 20160 B
    __shared__ __align__(16) float tpl[NT * TPL_STR];     // 1664 B

    const int bc  = blockIdx.x;          // b*256 + c, 0..2047
    const int tid = threadIdx.x;

    // ---- zero the whole padded plane (pads must be 0) ----
    for (int i = tid; i < LROWS * LSTR; i += 256) xpl[i] = 0.0f;
    __syncthreads();

    // ---- stage x interior: 1024 float4 loads, coalesced ----
    const float* xp = x + bc * PLANE;
    for (int i = tid; i < PLANE / 4; i += 256) {
        float4 v = ((const float4*)xp)[i];
        int row = i >> 4;              // 16 float4 per 64-wide row
        int c4  = (i & 15) << 2;
        *(float4*)&xpl[(row + 3) * LSTR + 4 + c4] = v;
    }

    // ---- stage all 8 templates for this (b,c) ----
    const float* tb = tm + bc * 49;
    for (int i = tid; i < NT * 49; i += 256) {
        int t = i / 49;
        int k = i - t * 49;
        tpl[t * TPL_STR + k] = tb[t * (NT * NC * 49) + k];
    }
    __syncthreads();

    // ---- compute geometry: 128 threads cover the plane per template ----
    // half 0 (tid 0..127, waves 0-1) does template 2*rnd+0,
    // half 1 (tid 128..255, waves 2-3) does template 2*rnd+1 (wave-uniform t).
    const int half = tid >> 7;
    const int lid  = tid & 127;
    const int tx   = lid & 15;           // col group: cols 4*tx..4*tx+3
    const int ty   = lid >> 4;           // row group: rows 8*ty..8*ty+7
    const int col0 = tx << 2;
    const int row0 = ty << 3;

    for (int rnd = 0; rnd < 4; ++rnd) {
        const int t = (rnd << 1) + half;

        // broadcast template taps into registers (12 x ds_read_b128 + 1 scalar,
        // same addr across the wave -> LDS broadcast)
        float w[49];
        const float4* wp = (const float4*)&tpl[t * TPL_STR];
        #pragma unroll
        for (int q = 0; q < 12; ++q) {
            float4 v = wp[q];
            w[4 * q + 0] = v.x; w[4 * q + 1] = v.y;
            w[4 * q + 2] = v.z; w[4 * q + 3] = v.w;
        }
        w[48] = tpl[t * TPL_STR + 48];

        float acc[8][4];
        #pragma unroll
        for (int r = 0; r < 8; ++r)
            #pragma unroll
            for (int j = 0; j < 4; ++j) acc[r][j] = 0.0f;

        // input rows for output rows row0..row0+7: LDS rows row0..row0+13
        #pragma unroll
        for (int ir = 0; ir < 14; ++ir) {
            const float* rowp = &xpl[(row0 + ir) * LSTR + col0];
            float xw[12];
            float4 a = *(const float4*)(rowp);
            float4 b = *(const float4*)(rowp + 4);
            float4 c = *(const float4*)(rowp + 8);
            xw[0] = a.x; xw[1]  = a.y; xw[2]  = a.z; xw[3]  = a.w;
            xw[4] = b.x; xw[5]  = b.y; xw[6]  = b.z; xw[7]  = b.w;
            xw[8] = c.x; xw[9]  = c.y; xw[10] = c.z; xw[11] = c.w;

            #pragma unroll
            for (int r = 0; r < 8; ++r) {
                const int ky = ir - r;            // compile-time after unroll
                if (ky >= 0 && ky < 7) {
                    #pragma unroll
                    for (int kx = 0; kx < 7; ++kx) {
                        const float tv = w[ky * 7 + kx];
                        #pragma unroll
                        for (int j = 0; j < 4; ++j)
                            acc[r][j] = fmaf(xw[j + kx + 1], tv, acc[r][j]);
                    }
                }
            }
        }

        // ---- store 8 rows x float4, coalesced across tx (256B runs) ----
        float* op = out + (size_t)(t * (BS * NC) + bc) * PLANE + row0 * HW + col0;
        #pragma unroll
        for (int r = 0; r < 8; ++r) {
            float4 v = make_float4(acc[r][0], acc[r][1], acc[r][2], acc[r][3]);
            *(float4*)(op + r * HW) = v;
        }
    }
}

extern "C" void kernel_launch(void* const* d_in, const int* in_sizes, int n_in,
                              void* d_out, int out_size, void* d_ws, size_t ws_size,
                              hipStream_t stream) {
    const float* x  = (const float*)d_in[0];
    const float* tm = (const float*)d_in[1];
    float* out = (float*)d_out;
    dwxcorr_kernel<<<BS * NC, 256, 0, stream>>>(x, tm, out);
}